// Round 7
// baseline (579.252 us; speedup 1.0000x reference)
//
#include <hip/hip_runtime.h>
#include <stdint.h>

#define B_ 2
#define H_ 16
#define S_ 2048
#define D_ 128

typedef float f32x4 __attribute__((ext_vector_type(4)));
typedef short bf16x8 __attribute__((ext_vector_type(8)));
typedef unsigned short u16x4 __attribute__((ext_vector_type(4)));
typedef int i32x4 __attribute__((ext_vector_type(4)));

__device__ __forceinline__ unsigned short f2bf(float x){
  union { float f; uint32_t u; } c; c.f = x;
  uint32_t u = c.u;
  uint32_t r = (u + 0x7FFFu + ((u >> 16) & 1u)) >> 16;
  return (unsigned short)r;
}

// ---- prep: K fp32 -> bf16 (same layout) ----
__global__ void kconv_kernel(const float* __restrict__ k, unsigned short* __restrict__ KB){
  size_t i = (size_t)blockIdx.x * 256 + threadIdx.x;   // 2,097,152 float4s exactly
  f32x4 v = __builtin_nontemporal_load(&((const f32x4*)k)[i]);
  u16x4 o; o[0]=f2bf(v.x); o[1]=f2bf(v.y); o[2]=f2bf(v.z); o[3]=f2bf(v.w);
  __builtin_nontemporal_store(o, &((u16x4*)KB)[i]);
}

// ---- prep: V fp32 [bh][t][d] -> VT bf16 [bh][d][t] ----
__global__ void vtrans_kernel(const float* __restrict__ v, unsigned short* __restrict__ VT){
  __shared__ float tile[64][73];          // pad 73: col-reads spread over banks
  int blk = blockIdx.x;                   // 2048 = 32 bh * 32 ttile * 2 dtile
  int bh = blk >> 6;
  int ts = (blk >> 1) & 31;
  int dsec = blk & 1;
  int t0 = ts*64, d0 = dsec*64;
  const float* vb = v + ((size_t)bh*S_ + t0)*D_ + d0;
  int tid = threadIdx.x;
  #pragma unroll
  for (int i=0;i<4;++i){
    int fi = i*256 + tid;                 // 1024 float4 per tile
    int r = fi >> 4;
    int c4 = (fi & 15) * 4;
    f32x4 val = __builtin_nontemporal_load((const f32x4*)(vb + (size_t)r*D_ + c4));
    tile[r][c4+0]=val.x; tile[r][c4+1]=val.y; tile[r][c4+2]=val.z; tile[r][c4+3]=val.w;
  }
  __syncthreads();
  unsigned short* ob = VT + ((size_t)bh*D_ + d0)*S_ + t0;
  #pragma unroll
  for (int i=0;i<4;++i){
    int ui = i*256 + tid;                 // 1024 ushort4 per tile
    int dr = ui >> 4;
    int tc = (ui & 15) * 4;
    u16x4 o;
    o[0] = f2bf(tile[tc+0][dr]);
    o[1] = f2bf(tile[tc+1][dr]);
    o[2] = f2bf(tile[tc+2][dr]);
    o[3] = f2bf(tile[tc+3][dr]);
    __builtin_nontemporal_store(o, (u16x4*)(ob + (size_t)dr*S_ + tc));
  }
}

// ---- prep: mask int32 [b][s][t] -> bitmask u64 [b][s][32 words] ----
__global__ void maskprep_kernel(const int* __restrict__ mask, unsigned long long* __restrict__ bits){
  int row = blockIdx.x;                   // B_*S_ = 4096 rows
  const int* mrow = mask + (size_t)row*S_;
  int w = threadIdx.x >> 6;
  int lane = threadIdx.x & 63;
  #pragma unroll
  for (int i=0;i<8;++i){
    int t = i*256 + threadIdx.x;
    unsigned long long bm = __ballot(__builtin_nontemporal_load(&mrow[t]) != 0);
    if (lane == 0) bits[(size_t)row*32 + i*4 + w] = bm;
  }
}

// ---- main fused kernel (split-t): partial l + partial W = mask@V over 16 tiles ----
__launch_bounds__(256, 4)
__global__ void fused_kernel(const float* __restrict__ q,
                             const unsigned long long* __restrict__ bits,
                             const unsigned short* __restrict__ KB,
                             const unsigned short* __restrict__ VT,
                             float* __restrict__ Wpart,
                             float* __restrict__ lpart)
{
  __shared__ unsigned char Ksm[64*256];    // [t][128 bf16], row-XOR-swizzled
  __shared__ unsigned char Vsm[128*128];   // [d][64 bf16],  row-XOR-swizzled
  const int tid = threadIdx.x;
  const int lane = tid & 63;
  const int w = tid >> 6;
  const int l16 = lane & 15;
  const int lhi = lane >> 4;

  // bijective XCD swizzle: grid=1024, 8 XCDs -> 128 consecutive logical
  // blocks per XCD = 4 bh's K/V (4 MB) resident in that XCD's L2
  const int orig = blockIdx.x;
  const int blk = (orig & 7) * 128 + (orig >> 3);
  const int bh = blk >> 5;
  const int r5 = blk & 31;
  const int qt = r5 >> 1;
  const int half = r5 & 1;
  const int b = bh >> 4;
  const int s0 = qt * 128;
  const int rowbase = s0 + 32*w;

  const float QS = 1.4426950408889634f / 11.313708498984761f;  // log2(e)/TEMP

  // Q fragments (2 rf x 4 ks), scaled into log2 domain
  bf16x8 qf[2][4];
  #pragma unroll
  for (int rf=0; rf<2; ++rf){
    const float* qp = q + ((size_t)bh*S_ + (rowbase + 16*rf + l16))*D_ + lhi*8;
    #pragma unroll
    for (int ks=0; ks<4; ++ks){
      f32x4 a0 = __builtin_nontemporal_load((const f32x4*)(qp + 32*ks));
      f32x4 a1 = __builtin_nontemporal_load((const f32x4*)(qp + 32*ks + 4));
      bf16x8 f;
      f[0]=(short)f2bf(a0.x*QS); f[1]=(short)f2bf(a0.y*QS);
      f[2]=(short)f2bf(a0.z*QS); f[3]=(short)f2bf(a0.w*QS);
      f[4]=(short)f2bf(a1.x*QS); f[5]=(short)f2bf(a1.y*QS);
      f[6]=(short)f2bf(a1.z*QS); f[7]=(short)f2bf(a1.w*QS);
      qf[rf][ks] = f;
    }
  }

  f32x4 Wacc[2][8];
  #pragma unroll
  for (int rf=0;rf<2;++rf)
    #pragma unroll
    for (int dc=0;dc<8;++dc){ f32x4 z = {0.f,0.f,0.f,0.f}; Wacc[rf][dc] = z; }
  float lrow[2][4];
  #pragma unroll
  for (int rf=0;rf<2;++rf)
    #pragma unroll
    for (int r=0;r<4;++r){ lrow[rf][r]=0.f; }

  const unsigned short* Kg = KB + (size_t)bh*S_*D_;
  const unsigned short* Vg = VT + (size_t)bh*D_*S_;
  const unsigned long long* bitsb = bits + (size_t)b*S_*32;   // 32 u64 words/row

  for (int j=0; j<16; ++j){
    const int it = half*16 + j;
    const int t0 = it*64;
    __syncthreads();
    // stage K tile (64 rows x 256B) and VT tile (128 rows x 128B), swizzled
    {
      const unsigned char* src = (const unsigned char*)(Kg + (size_t)t0*D_);
      #pragma unroll
      for (int i=0;i<4;++i){
        int chunk = i*256 + tid;        // 1024 chunks of 16B
        int r = chunk >> 4;
        int cb = (chunk & 15) << 4;
        i32x4 val = *(const i32x4*)(src + (size_t)r*256 + cb);
        *(i32x4*)(Ksm + r*256 + (cb ^ ((r&7)<<4))) = val;
      }
      const unsigned char* vsrc = (const unsigned char*)(Vg + t0);
      #pragma unroll
      for (int i=0;i<4;++i){
        int chunk = i*256 + tid;        // 1024 chunks of 16B
        int r = chunk >> 3;             // 128 rows x 8 chunks
        int cb = (chunk & 7) << 4;
        i32x4 val = *(const i32x4*)(vsrc + (size_t)r*(S_*2) + cb);
        *(i32x4*)(Vsm + r*128 + (cb ^ ((r&7)<<4))) = val;
      }
    }

    // mask words for this tile (one u64 = 64 t-bits per row)
    unsigned long long mbA[2];            // A-path: row rowbase+16rf+l16
    #pragma unroll
    for (int rf=0; rf<2; ++rf)
      mbA[rf] = bitsb[(size_t)(rowbase + 16*rf + l16)*32 + it];
    unsigned long long mbC[2][4];         // C-path: row rowbase+16rf+4*lhi+reg
    #pragma unroll
    for (int rf=0; rf<2; ++rf)
      #pragma unroll
      for (int reg=0; reg<4; ++reg)
        mbC[rf][reg] = bitsb[(size_t)(rowbase + 16*rf + 4*lhi + reg)*32 + it];

    __syncthreads();

    // QK^T -> S fragments (log2 domain)
    f32x4 Sacc[2][4];
    #pragma unroll
    for (int rf=0;rf<2;++rf)
      #pragma unroll
      for (int cf=0;cf<4;++cf){ f32x4 z = {0.f,0.f,0.f,0.f}; Sacc[rf][cf] = z; }
    #pragma unroll
    for (int cf=0; cf<4; ++cf){
      int t_l = 16*cf + l16;
      #pragma unroll
      for (int ks=0; ks<4; ++ks){
        int cb = 64*ks + lhi*16;
        bf16x8 bfr = *(const bf16x8*)(Ksm + t_l*256 + (cb ^ ((t_l&7)<<4)));
        Sacc[0][cf] = __builtin_amdgcn_mfma_f32_16x16x32_bf16(qf[0][ks], bfr, Sacc[0][cf], 0,0,0);
        Sacc[1][cf] = __builtin_amdgcn_mfma_f32_16x16x32_bf16(qf[1][ks], bfr, Sacc[1][cf], 0,0,0);
      }
    }

    // stats: no max needed (|score*log2e| <~ 17, fp32 sum safe).
    // bit set -> masked -> exp2(0)=1.0 == exp(1e-9) in fp32.
    #pragma unroll
    for (int rf=0; rf<2; ++rf){
      #pragma unroll
      for (int reg=0; reg<4; ++reg){
        uint32_t lo = (uint32_t)mbC[rf][reg];
        uint32_t hi = (uint32_t)(mbC[rf][reg] >> 32);
        uint32_t a = lo >> l16;
        uint32_t d = hi >> l16;
        float x0 = (a & 1u)        ? 0.f : Sacc[rf][0][reg];
        float x1 = ((a >> 16) & 1u)? 0.f : Sacc[rf][1][reg];
        float x2 = (d & 1u)        ? 0.f : Sacc[rf][2][reg];
        float x3 = ((d >> 16) & 1u)? 0.f : Sacc[rf][3][reg];
        float e0 = __builtin_amdgcn_exp2f(x0);
        float e1 = __builtin_amdgcn_exp2f(x1);
        float e2 = __builtin_amdgcn_exp2f(x2);
        float e3 = __builtin_amdgcn_exp2f(x3);
        lrow[rf][reg] += (e0+e1)+(e2+e3);
      }
    }

    // W += maskTile @ Vtile (A-fragment bf16 0/1 built from 8 bits per lane)
    #pragma unroll
    for (int ksw=0; ksw<2; ++ksw){
      bf16x8 am[2];
      #pragma unroll
      for (int rf=0; rf<2; ++rf){
        uint32_t word = (uint32_t)(mbA[rf] >> (32*ksw));
        uint32_t bt = (word >> (8*lhi)) & 0xFFu;
        union { bf16x8 v; uint32_t u[4]; } pk;
        pk.u[0] = (((bt>>0)&1u) | (((bt>>1)&1u)<<16)) * 0x3F80u;
        pk.u[1] = (((bt>>2)&1u) | (((bt>>3)&1u)<<16)) * 0x3F80u;
        pk.u[2] = (((bt>>4)&1u) | (((bt>>5)&1u)<<16)) * 0x3F80u;
        pk.u[3] = (((bt>>6)&1u) | (((bt>>7)&1u)<<16)) * 0x3F80u;
        am[rf] = pk.v;
      }
      #pragma unroll
      for (int dc=0; dc<8; ++dc){
        int d_l = 16*dc + l16;
        int cb = 64*ksw + lhi*16;
        bf16x8 bfr = *(const bf16x8*)(Vsm + d_l*128 + (cb ^ ((d_l&7)<<4)));
        Wacc[0][dc] = __builtin_amdgcn_mfma_f32_16x16x32_bf16(am[0], bfr, Wacc[0][dc], 0,0,0);
        Wacc[1][dc] = __builtin_amdgcn_mfma_f32_16x16x32_bf16(am[1], bfr, Wacc[1][dc], 0,0,0);
      }
    }
  }

  // partial row-sum across the 16-lane group -> lpart
  #pragma unroll
  for (int rf=0;rf<2;++rf){
    #pragma unroll
    for (int reg=0;reg<4;++reg){
      float l = lrow[rf][reg];
      l += __shfl_xor(l, 1);
      l += __shfl_xor(l, 2);
      l += __shfl_xor(l, 4);
      l += __shfl_xor(l, 8);
      if (l16 == 0){
        lpart[((size_t)half*B_*H_ + bh)*S_ + rowbase + 16*rf + 4*lhi + reg] = l;
      }
    }
  }
  // partial W -> Wpart[pidx][128][128]
  const size_t pidx = ((size_t)half << 9) + (size_t)bh*16 + qt;
  #pragma unroll
  for (int rf=0;rf<2;++rf){
    #pragma unroll
    for (int dc=0;dc<8;++dc){
      #pragma unroll
      for (int reg=0;reg<4;++reg){
        int lrw = 32*w + 16*rf + 4*lhi + reg;
        __builtin_nontemporal_store(Wacc[rf][dc][reg],
            &Wpart[(pidx*128 + lrw)*128 + 16*dc + l16]);
      }
    }
  }
}

// ---- reduce: out = (W0+W1)/(l0+l1), c_ws = 1/(l0+l1) ----
__global__ void reduce_kernel(const float* __restrict__ Wpart,
                              const float* __restrict__ lpart,
                              float* __restrict__ outp,
                              float* __restrict__ c_ws){
  int tg = blockIdx.x*256 + threadIdx.x;        // 524288 threads
  #pragma unroll
  for (int kk=0; kk<4; ++kk){
    int g = tg + kk*524288;                     // f32x4 index in [0, 2^21)
    int dq = g & 31;
    int srow = (g >> 5) & 2047;
    int bh = g >> 16;
    size_t pidx0 = (size_t)bh*16 + (srow >> 7);
    int rowin = srow & 127;
    f32x4 w0 = __builtin_nontemporal_load((const f32x4*)Wpart + (pidx0*128 + rowin)*32 + dq);
    f32x4 w1 = __builtin_nontemporal_load((const f32x4*)Wpart + ((pidx0+512)*128 + rowin)*32 + dq);
    float l0 = lpart[(size_t)bh*S_ + srow];
    float l1 = lpart[(size_t)(B_*H_ + bh)*S_ + srow];
    float c = 1.0f / (l0 + l1);
    f32x4 o = (w0 + w1) * c;
    __builtin_nontemporal_store(o, (f32x4*)outp + g);
    if (dq == 0) c_ws[(size_t)bh*S_ + srow] = c;
  }
}

// ---- atten output: atten[b,h,s,:] = c[b,h,s] * maskbit[b,s,:] ----
__global__ void atten_kernel(const unsigned long long* __restrict__ bits,
                             const float* __restrict__ c_ws,
                             float* __restrict__ atten){
  int blk = blockIdx.x;            // B_*S_ = 4096 blocks
  int bq = blk >> 11;
  int s  = blk & 2047;
  __shared__ float csm[16];
  if (threadIdx.x < 16)
    csm[threadIdx.x] = c_ws[((size_t)(bq*H_ + threadIdx.x))*S_ + s];
  __syncthreads();
  const unsigned long long* wrow = bits + ((size_t)bq*S_ + s)*32;
  for (int i = threadIdx.x; i < S_/4; i += 256){
    unsigned long long wv = wrow[i >> 4];
    uint32_t nib = (uint32_t)(wv >> ((i & 15)*4)) & 0xFu;
    #pragma unroll
    for (int h=0; h<H_; ++h){
      float c = csm[h];
      f32x4 o = { (nib&1u)?c:0.f, (nib&2u)?c:0.f, (nib&4u)?c:0.f, (nib&8u)?c:0.f };
      __builtin_nontemporal_store(o, ((f32x4*)(atten + (((size_t)(bq*H_ + h)*S_ + s)*S_))) + i);
    }
  }
}

extern "C" void kernel_launch(void* const* d_in, const int* in_sizes, int n_in,
                              void* d_out, int out_size, void* d_ws, size_t ws_size,
                              hipStream_t stream){
  const float* q = (const float*)d_in[0];
  const float* k = (const float*)d_in[1];
  const float* v = (const float*)d_in[2];
  const int* mask = (const int*)d_in[3];
  float* outp = (float*)d_out;
  float* atten = outp + (size_t)B_*H_*S_*D_;

  unsigned short* KB = (unsigned short*)d_ws;                         // 16.78 MB
  unsigned short* VT = KB + (size_t)B_*H_*S_*D_;                      // 16.78 MB
  float* c_ws = (float*)(VT + (size_t)B_*H_*S_*D_);                   // 0.26 MB
  unsigned long long* bits = (unsigned long long*)(c_ws + (size_t)B_*H_*S_);  // 1.05 MB
  float* lpart = (float*)(bits + (size_t)B_*S_*32);                   // 0.52 MB
  float* Wpart = lpart + (size_t)2*B_*H_*S_;                          // 67.1 MB

  hipLaunchKernelGGL(maskprep_kernel, dim3(4096), dim3(256), 0, stream, mask, bits);
  hipLaunchKernelGGL(kconv_kernel,  dim3(8192), dim3(256), 0, stream, k, KB);
  hipLaunchKernelGGL(vtrans_kernel, dim3(2048), dim3(256), 0, stream, v, VT);
  hipLaunchKernelGGL(fused_kernel,  dim3(1024), dim3(256), 0, stream, q, bits, KB, VT, Wpart, lpart);
  hipLaunchKernelGGL(reduce_kernel, dim3(2048), dim3(256), 0, stream, Wpart, lpart, outp, c_ws);
  hipLaunchKernelGGL(atten_kernel,  dim3(4096), dim3(256), 0, stream, bits, c_ws, atten);
}

// Round 8
// 265.498 us; speedup vs baseline: 2.1818x; 2.1818x over previous
//
#include <hip/hip_runtime.h>
#include <stdint.h>

#define B_ 2
#define H_ 16
#define S_ 2048
#define D_ 128

typedef float f32x4 __attribute__((ext_vector_type(4)));
typedef short bf16x8 __attribute__((ext_vector_type(8)));
typedef unsigned short u16x4 __attribute__((ext_vector_type(4)));
typedef int i32x4 __attribute__((ext_vector_type(4)));

__device__ __forceinline__ unsigned short f2bf(float x){
  union { float f; uint32_t u; } c; c.f = x;
  uint32_t u = c.u;
  uint32_t r = (u + 0x7FFFu + ((u >> 16) & 1u)) >> 16;
  return (unsigned short)r;
}

// ---- prep: K fp32 -> bf16 (same layout) ----
__global__ void kconv_kernel(const float* __restrict__ k, unsigned short* __restrict__ KB){
  size_t i = (size_t)blockIdx.x * 256 + threadIdx.x;   // 2,097,152 float4s exactly
  f32x4 v = __builtin_nontemporal_load(&((const f32x4*)k)[i]);
  u16x4 o; o[0]=f2bf(v.x); o[1]=f2bf(v.y); o[2]=f2bf(v.z); o[3]=f2bf(v.w);
  __builtin_nontemporal_store(o, &((u16x4*)KB)[i]);
}

// ---- prep: V fp32 [bh][t][d] -> VT bf16 [bh][d][t] ----
__global__ void vtrans_kernel(const float* __restrict__ v, unsigned short* __restrict__ VT){
  __shared__ float tile[64][73];          // pad 73: col-reads spread over banks
  int blk = blockIdx.x;                   // 2048 = 32 bh * 32 ttile * 2 dtile
  int bh = blk >> 6;
  int ts = (blk >> 1) & 31;
  int dsec = blk & 1;
  int t0 = ts*64, d0 = dsec*64;
  const float* vb = v + ((size_t)bh*S_ + t0)*D_ + d0;
  int tid = threadIdx.x;
  #pragma unroll
  for (int i=0;i<4;++i){
    int fi = i*256 + tid;                 // 1024 float4 per tile
    int r = fi >> 4;
    int c4 = (fi & 15) * 4;
    f32x4 val = __builtin_nontemporal_load((const f32x4*)(vb + (size_t)r*D_ + c4));
    tile[r][c4+0]=val.x; tile[r][c4+1]=val.y; tile[r][c4+2]=val.z; tile[r][c4+3]=val.w;
  }
  __syncthreads();
  unsigned short* ob = VT + ((size_t)bh*D_ + d0)*S_ + t0;
  #pragma unroll
  for (int i=0;i<4;++i){
    int ui = i*256 + tid;                 // 1024 ushort4 per tile
    int dr = ui >> 4;
    int tc = (ui & 15) * 4;
    u16x4 o;
    o[0] = f2bf(tile[tc+0][dr]);
    o[1] = f2bf(tile[tc+1][dr]);
    o[2] = f2bf(tile[tc+2][dr]);
    o[3] = f2bf(tile[tc+3][dr]);
    __builtin_nontemporal_store(o, (u16x4*)(ob + (size_t)dr*S_ + tc));
  }
}

// ---- prep: mask int32 [b][s][t] -> bitmask u64 [b][s][32 words] ----
__global__ void maskprep_kernel(const int* __restrict__ mask, unsigned long long* __restrict__ bits){
  int row = blockIdx.x;                   // B_*S_ = 4096 rows
  const int* mrow = mask + (size_t)row*S_;
  int w = threadIdx.x >> 6;
  int lane = threadIdx.x & 63;
  #pragma unroll
  for (int i=0;i<8;++i){
    int t = i*256 + threadIdx.x;
    unsigned long long bm = __ballot(__builtin_nontemporal_load(&mrow[t]) != 0);
    if (lane == 0) bits[(size_t)row*32 + i*4 + w] = bm;
  }
}

// ---- main fused kernel: 8 waves, T14 reg-staged pipeline, raw mid-barrier ----
__launch_bounds__(512, 4)
__global__ void fused_kernel(const float* __restrict__ q,
                             const unsigned long long* __restrict__ bits,
                             const unsigned short* __restrict__ KB,
                             const unsigned short* __restrict__ VT,
                             float* __restrict__ outp,
                             float* __restrict__ c_ws)
{
  __shared__ unsigned char Ksm[64*256];    // [t][128 bf16], row-XOR-swizzled
  __shared__ unsigned char Vsm[128*128];   // [d][64 bf16],  row-XOR-swizzled
  const int tid = threadIdx.x;
  const int lane = tid & 63;
  const int w = tid >> 6;                  // 8 waves
  const int l16 = lane & 15;
  const int lhi = lane >> 4;

  // bijective XCD swizzle: grid=512, 8 XCDs -> 64 consecutive logical blocks/XCD
  const int orig = blockIdx.x;
  const int blk = (orig & 7) * 64 + (orig >> 3);
  const int bh = blk >> 4;
  const int qt = blk & 15;
  const int b = bh >> 4;
  const int s0 = qt * 128;
  const int rowbase = s0 + 16*w;           // each wave owns 16 rows

  const float QS = 1.4426950408889634f / 11.313708498984761f;  // log2(e)/TEMP

  // Q fragments (4 ks), scaled into log2 domain
  bf16x8 qf[4];
  {
    const float* qp = q + ((size_t)bh*S_ + (rowbase + l16))*D_ + lhi*8;
    #pragma unroll
    for (int ks=0; ks<4; ++ks){
      f32x4 a0 = __builtin_nontemporal_load((const f32x4*)(qp + 32*ks));
      f32x4 a1 = __builtin_nontemporal_load((const f32x4*)(qp + 32*ks + 4));
      bf16x8 f;
      f[0]=(short)f2bf(a0.x*QS); f[1]=(short)f2bf(a0.y*QS);
      f[2]=(short)f2bf(a0.z*QS); f[3]=(short)f2bf(a0.w*QS);
      f[4]=(short)f2bf(a1.x*QS); f[5]=(short)f2bf(a1.y*QS);
      f[6]=(short)f2bf(a1.z*QS); f[7]=(short)f2bf(a1.w*QS);
      qf[ks] = f;
    }
  }

  f32x4 Wacc[8];
  #pragma unroll
  for (int dc=0;dc<8;++dc){ f32x4 z = {0.f,0.f,0.f,0.f}; Wacc[dc] = z; }
  float lrow[4] = {0.f,0.f,0.f,0.f};

  const unsigned short* Kg = KB + (size_t)bh*S_*D_;
  const unsigned short* Vg = VT + (size_t)bh*D_*S_;
  const unsigned long long* bitsb = bits + (size_t)b*S_*32;   // 32 u64 words/row

  // per-thread staging slots: K 1024 chunks/512 thr = 2, V same
  int kr[2], kcb[2], vr[2], vcb[2];
  #pragma unroll
  for (int i=0;i<2;++i){
    int chunk = i*512 + tid;
    kr[i] = chunk >> 4;  kcb[i] = (chunk & 15) << 4;   // K: 64 rows x 16 chunks
    vr[i] = chunk >> 3;  vcb[i] = (chunk & 7) << 4;    // V: 128 rows x 8 chunks
  }
  i32x4 kst[2], vst[2];

  auto loadstage = [&](int it){
    const unsigned char* ksrc = (const unsigned char*)Kg + (size_t)it*64*256;
    const unsigned char* vsrc = (const unsigned char*)(Vg + (size_t)it*64);
    #pragma unroll
    for (int i=0;i<2;++i)
      kst[i] = *(const i32x4*)(ksrc + (size_t)kr[i]*256 + kcb[i]);
    #pragma unroll
    for (int i=0;i<2;++i)
      vst[i] = *(const i32x4*)(vsrc + (size_t)vr[i]*(S_*2) + vcb[i]);
  };
  auto writestage = [&](){
    #pragma unroll
    for (int i=0;i<2;++i)
      *(i32x4*)(&Ksm[kr[i]*256 + (kcb[i] ^ ((kr[i]&7)<<4))]) = kst[i];
    #pragma unroll
    for (int i=0;i<2;++i)
      *(i32x4*)(&Vsm[vr[i]*128 + (vcb[i] ^ ((vr[i]&7)<<4))]) = vst[i];
  };

  loadstage(0);

  for (int it=0; it<32; ++it){
    const int t0 = it*64;
    __syncthreads();            // full drain: staged regs ready (vmcnt), prior reads done (lgkm)
    writestage();               // ds_write tile it

    // mask bit loads for THIS tile, issued BEFORE the prefetch (FIFO: consuming
    // them later does not retire the stage loads)
    unsigned long long mbA = bitsb[(size_t)(rowbase + l16)*32 + it];
    unsigned long long mbC[4];
    #pragma unroll
    for (int reg=0; reg<4; ++reg)
      mbC[reg] = bitsb[(size_t)(rowbase + 4*lhi + reg)*32 + it];

    if (it+1 < 32) loadstage(it+1);   // prefetch: stays in flight through compute

    asm volatile("s_waitcnt lgkmcnt(0)" ::: "memory");   // my ds_writes done (NOT vmcnt)
    __builtin_amdgcn_sched_barrier(0);
    __builtin_amdgcn_s_barrier();                        // raw: no vmcnt drain
    __builtin_amdgcn_sched_barrier(0);

    // QK^T -> S fragments (log2 domain)
    f32x4 Sacc[4];
    #pragma unroll
    for (int cf=0;cf<4;++cf){ f32x4 z = {0.f,0.f,0.f,0.f}; Sacc[cf] = z; }
    __builtin_amdgcn_s_setprio(1);
    #pragma unroll
    for (int cf=0; cf<4; ++cf){
      int t_l = 16*cf + l16;
      #pragma unroll
      for (int ks=0; ks<4; ++ks){
        int cb = 64*ks + lhi*16;
        bf16x8 bfr = *(const bf16x8*)(&Ksm[t_l*256 + (cb ^ ((t_l&7)<<4))]);
        Sacc[cf] = __builtin_amdgcn_mfma_f32_16x16x32_bf16(qf[ks], bfr, Sacc[cf], 0,0,0);
      }
    }
    __builtin_amdgcn_s_setprio(0);

    // stats: no max needed (|score*log2e| <~ 17, fp32 sum safe).
    // bit set -> masked -> exp2(0)=1.0 == exp(1e-9) in fp32.
    #pragma unroll
    for (int reg=0; reg<4; ++reg){
      uint32_t lo = (uint32_t)mbC[reg];
      uint32_t hi = (uint32_t)(mbC[reg] >> 32);
      uint32_t a = lo >> l16;
      uint32_t d = hi >> l16;
      float x0 = (a & 1u)        ? 0.f : Sacc[0][reg];
      float x1 = ((a >> 16) & 1u)? 0.f : Sacc[1][reg];
      float x2 = (d & 1u)        ? 0.f : Sacc[2][reg];
      float x3 = ((d >> 16) & 1u)? 0.f : Sacc[3][reg];
      float e0 = __builtin_amdgcn_exp2f(x0);
      float e1 = __builtin_amdgcn_exp2f(x1);
      float e2 = __builtin_amdgcn_exp2f(x2);
      float e3 = __builtin_amdgcn_exp2f(x3);
      lrow[reg] += (e0+e1)+(e2+e3);
    }

    // W += maskTile @ Vtile (A-fragment bf16 0/1 built from 8 bits per lane)
    #pragma unroll
    for (int ksw=0; ksw<2; ++ksw){
      uint32_t word = (uint32_t)(mbA >> (32*ksw));
      uint32_t bt = (word >> (8*lhi)) & 0xFFu;
      union { bf16x8 v; uint32_t u[4]; } pk;
      pk.u[0] = (((bt>>0)&1u) | (((bt>>1)&1u)<<16)) * 0x3F80u;
      pk.u[1] = (((bt>>2)&1u) | (((bt>>3)&1u)<<16)) * 0x3F80u;
      pk.u[2] = (((bt>>4)&1u) | (((bt>>5)&1u)<<16)) * 0x3F80u;
      pk.u[3] = (((bt>>6)&1u) | (((bt>>7)&1u)<<16)) * 0x3F80u;
      __builtin_amdgcn_s_setprio(1);
      #pragma unroll
      for (int dc=0; dc<8; ++dc){
        int d_l = 16*dc + l16;
        int cb = 64*ksw + lhi*16;
        bf16x8 bfr = *(const bf16x8*)(&Vsm[d_l*128 + (cb ^ ((d_l&7)<<4))]);
        Wacc[dc] = __builtin_amdgcn_mfma_f32_16x16x32_bf16(pk.v, bfr, Wacc[dc], 0,0,0);
      }
      __builtin_amdgcn_s_setprio(0);
    }
  }

  // final row-sum across the 16-lane group, c = 1/l
  float cval[4];
  #pragma unroll
  for (int reg=0;reg<4;++reg){
    float l = lrow[reg];
    l += __shfl_xor(l, 1);
    l += __shfl_xor(l, 2);
    l += __shfl_xor(l, 4);
    l += __shfl_xor(l, 8);
    float c = 1.0f / l;
    cval[reg] = c;
    if (l16 == 0){
      c_ws[(size_t)bh*S_ + rowbase + 4*lhi + reg] = c;
    }
  }
  // out = c * W
  #pragma unroll
  for (int dc=0;dc<8;++dc){
    #pragma unroll
    for (int reg=0;reg<4;++reg){
      int srow = rowbase + 4*lhi + reg;
      __builtin_nontemporal_store(cval[reg]*Wacc[dc][reg],
                                  &outp[((size_t)bh*S_ + srow)*D_ + 16*dc + l16]);
    }
  }
}

// ---- atten output: atten[b,h,s,:] = c[b,h,s] * maskbit[b,s,:] ----
__global__ void atten_kernel(const unsigned long long* __restrict__ bits,
                             const float* __restrict__ c_ws,
                             float* __restrict__ atten){
  int blk = blockIdx.x;            // B_*S_ = 4096 blocks
  int bq = blk >> 11;
  int s  = blk & 2047;
  __shared__ float csm[16];
  if (threadIdx.x < 16)
    csm[threadIdx.x] = c_ws[((size_t)(bq*H_ + threadIdx.x))*S_ + s];
  __syncthreads();
  const unsigned long long* wrow = bits + ((size_t)bq*S_ + s)*32;
  for (int i = threadIdx.x; i < S_/4; i += 256){
    unsigned long long wv = wrow[i >> 4];
    uint32_t nib = (uint32_t)(wv >> ((i & 15)*4)) & 0xFu;
    #pragma unroll
    for (int h=0; h<H_; ++h){
      float c = csm[h];
      f32x4 o = { (nib&1u)?c:0.f, (nib&2u)?c:0.f, (nib&4u)?c:0.f, (nib&8u)?c:0.f };
      __builtin_nontemporal_store(o, ((f32x4*)(atten + (((size_t)(bq*H_ + h)*S_ + s)*S_))) + i);
    }
  }
}

extern "C" void kernel_launch(void* const* d_in, const int* in_sizes, int n_in,
                              void* d_out, int out_size, void* d_ws, size_t ws_size,
                              hipStream_t stream){
  const float* q = (const float*)d_in[0];
  const float* k = (const float*)d_in[1];
  const float* v = (const float*)d_in[2];
  const int* mask = (const int*)d_in[3];
  float* outp = (float*)d_out;
  float* atten = outp + (size_t)B_*H_*S_*D_;

  unsigned short* KB = (unsigned short*)d_ws;                         // 16.78 MB
  unsigned short* VT = KB + (size_t)B_*H_*S_*D_;                      // 16.78 MB
  float* c_ws = (float*)(VT + (size_t)B_*H_*S_*D_);                   // 0.26 MB
  unsigned long long* bits = (unsigned long long*)(c_ws + (size_t)B_*H_*S_);  // 1.05 MB

  hipLaunchKernelGGL(maskprep_kernel, dim3(4096), dim3(256), 0, stream, mask, bits);
  hipLaunchKernelGGL(kconv_kernel,  dim3(8192), dim3(256), 0, stream, k, KB);
  hipLaunchKernelGGL(vtrans_kernel, dim3(2048), dim3(256), 0, stream, v, VT);
  hipLaunchKernelGGL(fused_kernel,  dim3(512),  dim3(512), 0, stream, q, bits, KB, VT, outp, c_ws);
  hipLaunchKernelGGL(atten_kernel,  dim3(4096), dim3(256), 0, stream, bits, c_ws, atten);
}